// Round 4
// baseline (548.036 us; speedup 1.0000x reference)
//
#include <hip/hip_runtime.h>
#include <hip/hip_bf16.h>
#include <math.h>

// Problem constants
#define HID   64
#define VOCABN 64
#define INNER 24
#define SEQN  32
#define CAPN  8
#define NPOS  17
#define BATCHN 8192

typedef float f32x4 __attribute__((ext_vector_type(4)));

// all-reduce (sum) across the full 64-lane wave
__device__ __forceinline__ float allred64(float x) {
  x += __shfl_xor(x, 1);
  x += __shfl_xor(x, 2);
  x += __shfl_xor(x, 4);
  x += __shfl_xor(x, 8);
  x += __shfl_xor(x, 16);
  x += __shfl_xor(x, 32);
  return x;
}

// ---------- Kernel 1: per-token encoder table (pure f32) ----------
// enc depends only on the token id: enc_tab[v] = LN(h + FF(h)), h = embed[v].
// One block, 256 threads. All math f32 to match the np reference.
__global__ __launch_bounds__(256) void build_table(
    const float* __restrict__ embed,    // [64][64]
    const float* __restrict__ ff_w1,    // [64][128]
    const float* __restrict__ ff_b1,    // [128]
    const float* __restrict__ ff_w2,    // [128][64]
    const float* __restrict__ ff_b2,    // [64]
    const float* __restrict__ ln_g,     // [64]
    const float* __restrict__ ln_b,     // [64]
    float* __restrict__ etab)           // [64][64]
{
  __shared__ float A1s[64][132];   // relu(h@W1+b1), pad to 132
  __shared__ float xs [64][68];    // h + f, pad to 68
  const int t = threadIdx.x;

  // phase 1: A1[r][n] over 64 rows x 128 cols; thread = (rg, n)
  {
    int n = t & 127, rg = t >> 7;
    for (int rr = 0; rr < 32; ++rr) {
      int r = rg * 32 + rr;
      float acc = ff_b1[n];
      for (int k = 0; k < 64; ++k)
        acc = fmaf(embed[r * 64 + k], ff_w1[k * 128 + n], acc);
      A1s[r][n] = fmaxf(acc, 0.f);
    }
  }
  __syncthreads();

  // phase 2: x[r][n] = h[r][n] + (A1 @ W2)[r][n] + b2[n]
  {
    int n = t & 63, rg = t >> 6;
    for (int rr = 0; rr < 16; ++rr) {
      int r = rg * 16 + rr;
      float acc = ff_b2[n];
      for (int k = 0; k < 128; ++k)
        acc = fmaf(A1s[r][k], ff_w2[k * 64 + n], acc);
      xs[r][n] = acc + embed[r * 64 + n];
    }
  }
  __syncthreads();

  // phase 3: LayerNorm per row (two-pass, matches reference formula).
  // thread t: row = t>>2, owns cols c4+4j; reduce within aligned 4-lane group.
  {
    int r = t >> 2, c4 = t & 3;
    float s1 = 0.f;
    for (int j = 0; j < 16; ++j) s1 += xs[r][c4 + 4 * j];
    s1 += __shfl_xor(s1, 1);
    s1 += __shfl_xor(s1, 2);
    float mu = s1 * 0.015625f;
    float s2 = 0.f;
    for (int j = 0; j < 16; ++j) {
      float d = xs[r][c4 + 4 * j] - mu;
      s2 = fmaf(d, d, s2);
    }
    s2 += __shfl_xor(s2, 1);
    s2 += __shfl_xor(s2, 2);
    float var = s2 * 0.015625f;
    float rs  = rsqrtf(var + 1e-5f);
    for (int j = 0; j < 16; ++j) {
      int c = c4 + 4 * j;
      etab[r * 64 + c] = fmaf((xs[r][c] - mu) * rs, ln_g[c], ln_b[c]);
    }
  }
}

// ---------- Kernel 2: per-sample 8-step Adam + final projection ----------
__device__ __forceinline__ void adam_upd(float& p, float& m, float& v, float g,
                                         float cm, float sb) {
  m = fmaf(0.9f, m, 0.1f * g);
  v = fmaf(0.999f, v, (0.001f * g) * g);
  float den = fmaf(sqrtf(v), sb, 1e-8f);
  p = p - (cm * m) / den;
}

__global__ __launch_bounds__(256, 2) void adapt_kernel(
    const int* __restrict__ seqs,       // [BATCH][32]
    const float* __restrict__ etab,     // [64][64]
    const float* __restrict__ mlp_w1,   // [64][24]
    const float* __restrict__ mlp_b1,   // [24]
    const float* __restrict__ mlp_w2,   // [24][64]
    const float* __restrict__ mlp_b2,   // [64]
    const float* __restrict__ out_w,    // [64][64]
    const float* __restrict__ out_b,    // [64]
    float* __restrict__ out)            // [BATCH][64]
{
  __shared__ float tab[64 * 64];       // token -> enc row
  const int t = threadIdx.x;

  // stage table: 256 threads x 4 f32x4
  {
    const f32x4* src = (const f32x4*)etab;
    f32x4* dst = (f32x4*)tab;
    #pragma unroll
    for (int i = 0; i < 4; ++i) dst[t + 256 * i] = src[t + 256 * i];
  }
  __syncthreads();

  const int lane = t & 63;
  const int wv   = t >> 6;
  const int s    = blockIdx.x * 4 + wv;

  // token ids for positions 14..30 live in lanes 0..16
  int tok = 0;
  if (lane < NPOS) tok = seqs[s * SEQN + 14 + lane];

  // lane j owns: w1 row j, w2 column j, b2[j]; lanes<24 own b1[lane]
  float w1r[24], m1[24], v1[24], w2c[24], m2[24], v2[24];
  #pragma unroll
  for (int i = 0; i < 24; ++i) {
    w1r[i] = mlp_w1[lane * 24 + i];
    w2c[i] = mlp_w2[i * 64 + lane];
    m1[i] = 0.f; v1[i] = 0.f; m2[i] = 0.f; v2[i] = 0.f;
  }
  float b2o = mlp_b2[lane];
  float b1o = (lane < 24) ? mlp_b1[lane] : 0.f;
  float mb1 = 0.f, vb1 = 0.f, mb2 = 0.f, vb2 = 0.f;
  float pb1 = 1.f, pb2 = 1.f;

  #pragma unroll 1
  for (int st = 0; st < 8; ++st) {
    int tkk = __shfl(tok, 2 * st);
    int tvv = __shfl(tok, 2 * st + 1);
    float kj = tab[tkk * 64 + lane];
    float vj = tab[tvv * 64 + lane];

    // forward: z = W1^T k + b1  (64-lane reduce, replicated)
    float zp[24];
    #pragma unroll
    for (int i = 0; i < 24; ++i) zp[i] = kj * w1r[i];
    #pragma unroll
    for (int i = 0; i < 24; ++i) zp[i] += (lane == i) ? b1o : 0.f;
    #pragma unroll
    for (int i = 0; i < 24; ++i) zp[i] = allred64(zp[i]);

    float a[24];
    #pragma unroll
    for (int i = 0; i < 24; ++i) a[i] = fmaxf(zp[i], 0.f);

    float y = b2o;
    #pragma unroll
    for (int i = 0; i < 24; ++i) y = fmaf(a[i], w2c[i], y);
    float dy = (y - vj) * 0.03125f;   // 2/64

    // backward: da = W2 dy (reduce), dz = da * (z>0)
    float dz[24];
    #pragma unroll
    for (int i = 0; i < 24; ++i) dz[i] = w2c[i] * dy;
    #pragma unroll
    for (int i = 0; i < 24; ++i) dz[i] = allred64(dz[i]);
    #pragma unroll
    for (int i = 0; i < 24; ++i) dz[i] = (a[i] > 0.f) ? dz[i] : 0.f;

    // Adam step st+1
    pb1 *= 0.9f; pb2 *= 0.999f;
    float cm = 0.05f / (1.f - pb1);      // LR / bc1
    float sb = 1.f / sqrtf(1.f - pb2);   // 1/sqrt(bc2)
    #pragma unroll
    for (int i = 0; i < 24; ++i) adam_upd(w1r[i], m1[i], v1[i], kj * dz[i], cm, sb);
    #pragma unroll
    for (int i = 0; i < 24; ++i) adam_upd(w2c[i], m2[i], v2[i], a[i] * dy, cm, sb);
    adam_upd(b2o, mb2, vb2, dy, cm, sb);
    float gb1 = 0.f;
    #pragma unroll
    for (int i = 0; i < 24; ++i) gb1 = (lane == i) ? dz[i] : gb1;
    adam_upd(b1o, mb1, vb1, gb1, cm, sb);   // lanes>=24: g=0 -> no-op
  }

  // final forward with q (position 30 = lane 16's token)
  int tq = __shfl(tok, 16);
  float qj = tab[tq * 64 + lane];
  float zp[24];
  #pragma unroll
  for (int i = 0; i < 24; ++i) zp[i] = qj * w1r[i];
  #pragma unroll
  for (int i = 0; i < 24; ++i) zp[i] += (lane == i) ? b1o : 0.f;
  #pragma unroll
  for (int i = 0; i < 24; ++i) zp[i] = allred64(zp[i]);
  float hq = b2o;
  #pragma unroll
  for (int i = 0; i < 24; ++i) hq = fmaf(fmaxf(zp[i], 0.f), w2c[i], hq);

  // out[s][c] = sum_j hq[j] * out_w[j][c] + out_b[c]   (lane = c)
  float acc = out_b[lane];
  #pragma unroll 8
  for (int j = 0; j < 64; ++j)
    acc = fmaf(__shfl(hq, j), out_w[j * 64 + lane], acc);
  out[(size_t)s * 64 + lane] = acc;
}

extern "C" void kernel_launch(void* const* d_in, const int* in_sizes, int n_in,
                              void* d_out, int out_size, void* d_ws, size_t ws_size,
                              hipStream_t stream) {
  const int*   seqs   = (const int*)d_in[0];
  const float* embed  = (const float*)d_in[1];
  const float* ff_w1  = (const float*)d_in[2];
  const float* ff_b1  = (const float*)d_in[3];
  const float* ff_w2  = (const float*)d_in[4];
  const float* ff_b2  = (const float*)d_in[5];
  const float* ln_g   = (const float*)d_in[6];
  const float* ln_b   = (const float*)d_in[7];
  const float* mlp_w1 = (const float*)d_in[8];
  const float* mlp_b1 = (const float*)d_in[9];
  const float* mlp_w2 = (const float*)d_in[10];
  const float* mlp_b2 = (const float*)d_in[11];
  const float* out_w  = (const float*)d_in[12];
  const float* out_b  = (const float*)d_in[13];

  float* etab = (float*)d_ws;   // 64*64 f32 = 16 KB

  build_table<<<1, 256, 0, stream>>>(
      embed, ff_w1, ff_b1, ff_w2, ff_b2, ln_g, ln_b, etab);
  adapt_kernel<<<BATCHN / 4, 256, 0, stream>>>(
      seqs, etab, mlp_w1, mlp_b1, mlp_w2, mlp_b2, out_w, out_b,
      (float*)d_out);
}